// Round 5
// baseline (512.364 us; speedup 1.0000x reference)
//
#include <hip/hip_runtime.h>
#include <stdint.h>

typedef unsigned int uint;
typedef unsigned short ushort;

#define GD   96
#define GD2  (GD*GD)           // 9216
#define GSP  (GD*GD*GD)        // 884736 spatial cells
#define NPTS 1000000
#define WIN_ELTS 8192          // padded w_in frags: 64x128
#define WH_ELTS  16384         // 128x128
#define WFRAG_OFF (GSP*16)     // ushort offset of weight frags in ws
#define WFRAG_N  (WIN_ELTS + 3*WH_ELTS)   // 57344 ushorts
#define ACT_OFF  (WFRAG_OFF + WFRAG_N)    // ushort offset of staged act rows

#define PW   128               // points per wave (proven geometry)
#define ROWB 272               // LDS activation row stride bytes (136 bf16: 128 + 8 pad)
#define LDS_BYTES (4*PW*ROWB)  // 139264
#define NROWS (1954*512)       // 1,000,448 staged rows (covers mlp grid tail)

typedef __attribute__((ext_vector_type(8))) short short8;
typedef __attribute__((ext_vector_type(4))) float f32x4;

__device__ __forceinline__ uint f2bf(float x) {           // fp32 -> bf16 (RNE)
  uint u = __float_as_uint(x);
  return (u + 0x7fffu + ((u >> 16) & 1u)) >> 16;
}

// ---- pre-pass 1: feature grid [C,D,H,W] f32 -> [D,H,W,C] bf16 ----
__global__ void k_grid_pack(const float* __restrict__ g, ushort* __restrict__ o) {
  int sp = blockIdx.x * 256 + threadIdx.x;   // 0..884735
  uint pk[8];
#pragma unroll
  for (int c = 0; c < 16; c += 2) {
    float a = g[(size_t)c * GSP + sp];
    float b = g[(size_t)(c + 1) * GSP + sp];
    pk[c >> 1] = f2bf(a) | (f2bf(b) << 16);
  }
  uint4* dst = (uint4*)(o + (size_t)sp * 16);
  dst[0] = make_uint4(pk[0], pk[1], pk[2], pk[3]);
  dst[1] = make_uint4(pk[4], pk[5], pk[6], pk[7]);
}

// ---- pre-pass 2: weights -> MFMA B-fragment-packed bf16 ----
__global__ void k_w_pack(const float* __restrict__ win, const float* __restrict__ h0,
                         const float* __restrict__ h1, const float* __restrict__ h2,
                         ushort* __restrict__ o) {
  int tid = blockIdx.x * 256 + threadIdx.x;  // < 57344
  int lane = (tid >> 3) & 63, j = tid & 7;
  int q = lane >> 4, cc = lane & 15;
  float v;
  if (tid < WIN_ELTS) {
    int blk = tid >> 9;
    int t = blk >> 1, s = blk & 1;
    int k = s * 32 + q * 8 + j, n = t * 16 + cc;
    v = (k < 52) ? win[k * 128 + n] : 0.f;
  } else {
    int f2 = tid - WIN_ELTS;
    int l = f2 >> 14, r = f2 & 16383;
    int blk = r >> 9;
    int t = blk >> 2, s = blk & 3;
    int k = s * 32 + q * 8 + j, n = t * 16 + cc;
    const float* w = (l == 0) ? h0 : ((l == 1) ? h1 : h2);
    v = w[k * 128 + n];
  }
  o[tid] = (ushort)f2bf(v);
}

#define ACC8(off, U, W) {                                  \
  fv[(off)+0] += (W) * __uint_as_float((U).x << 16);       \
  fv[(off)+1] += (W) * __uint_as_float((U).x & 0xffff0000u);\
  fv[(off)+2] += (W) * __uint_as_float((U).y << 16);       \
  fv[(off)+3] += (W) * __uint_as_float((U).y & 0xffff0000u);\
  fv[(off)+4] += (W) * __uint_as_float((U).z << 16);       \
  fv[(off)+5] += (W) * __uint_as_float((U).z & 0xffff0000u);\
  fv[(off)+6] += (W) * __uint_as_float((U).w << 16);       \
  fv[(off)+7] += (W) * __uint_as_float((U).w & 0xffff0000u);\
}

// ---- gather + PE: one point per thread, no LDS, high occupancy ----
// Writes 64-col bf16 input row (128 B) per point to global staging.
__global__ void k_gather(const float* __restrict__ x,
                         const ushort* __restrict__ gridb,
                         ushort* __restrict__ actg) {
  const int p = blockIdx.x * 256 + threadIdx.x;   // 0..NROWS-1
  if (p >= NROWS) return;
  const int pc = min(p, NPTS - 1);
  const float px = x[pc * 3 + 0];
  const float py = x[pc * 3 + 1];
  const float pz = x[pc * 3 + 2];
  float fx = (px + 1.0f) * 0.5f * 95.0f;   // x -> W
  float fy = (py + 1.0f) * 0.5f * 95.0f;   // y -> H
  float fz = (pz + 1.0f) * 0.5f * 95.0f;   // z -> D
  float x0f = floorf(fx), y0f = floorf(fy), z0f = floorf(fz);
  float tx = fx - x0f, ty = fy - y0f, tz = fz - z0f;
  int x0i = min(max((int)x0f, 0), 95);
  int y0i = min(max((int)y0f, 0), 95);
  int z0i = min(max((int)z0f, 0), 95);
  int x1i = min(x0i + 1, 95);
  int y1i = min(y0i + 1, 95);
  int z1i = min(z0i + 1, 95);
  float fv[16];
#pragma unroll
  for (int k = 0; k < 16; ++k) fv[k] = 0.f;
#pragma unroll
  for (int dz = 0; dz < 2; ++dz) {
    const int zi = dz ? z1i : z0i;
    const float wz = dz ? tz : (1.f - tz);
#pragma unroll
    for (int dy = 0; dy < 2; ++dy) {
      const int yi = dy ? y1i : y0i;
      const float wzy = wz * (dy ? ty : (1.f - ty));
      const ushort* r0 = gridb + (size_t)(zi * GD2 + yi * GD + x0i) * 16;
      const ushort* r1 = gridb + (size_t)(zi * GD2 + yi * GD + x1i) * 16;
      uint4 a0 = *(const uint4*)r0;
      uint4 a1 = *(const uint4*)(r0 + 8);
      uint4 b0 = *(const uint4*)r1;
      uint4 b1 = *(const uint4*)(r1 + 8);
      const float w0 = wzy * (1.f - tx), w1 = wzy * tx;
      ACC8(0, a0, w0); ACC8(8, a1, w0);
      ACC8(0, b0, w1); ACC8(8, b1, w1);
    }
  }
  uint pk[32];
#pragma unroll
  for (int i = 0; i < 6; ++i) {
    const float fr = 3.14159265358979323846f * (float)(1 << i);
    pk[i*3+0] = f2bf(__sinf(px*fr)) | (f2bf(__sinf(py*fr)) << 16);
    pk[i*3+1] = f2bf(__sinf(pz*fr)) | (f2bf(__cosf(px*fr)) << 16);
    pk[i*3+2] = f2bf(__cosf(py*fr)) | (f2bf(__cosf(pz*fr)) << 16);
  }
#pragma unroll
  for (int j = 0; j < 8; ++j)
    pk[18+j] = f2bf(fv[2*j]) | (f2bf(fv[2*j+1]) << 16);
#pragma unroll
  for (int j = 26; j < 32; ++j) pk[j] = 0u;   // cols 52..63 zero-pad
  uint4* dst = (uint4*)(actg + (size_t)p * 64);
#pragma unroll
  for (int k = 0; k < 8; ++k)
    dst[k] = make_uint4(pk[4*k+0], pk[4*k+1], pk[4*k+2], pk[4*k+3]);
}

#define MFMA(A,B,C) __builtin_amdgcn_mfma_f32_16x16x32_bf16((A),(B),(C),0,0,0)

// ---- MLP kernel: 4 waves x 128 pts/wave; layer-in A from staged global ----
// Hidden-layer code byte-identical to the proven round-4 kernel.
__global__ __launch_bounds__(256, 1) void k_mlp(
    const ushort* __restrict__ actg, const float* __restrict__ wout,
    const ushort* __restrict__ wfrag, float* __restrict__ out) {
  extern __shared__ char smem[];
  const int wave = threadIdx.x >> 6;
  const int lane = threadIdx.x & 63;
  const int q = lane >> 4, c = lane & 15;
  char* act = smem + wave * (PW * ROWB);
  const int base = blockIdx.x * (4 * PW) + wave * PW;

  // ======== layer-in: X[128x64] @ w_in[64x128] -> relu -> act(LDS) ========
  {
    short8 bw[16];
#pragma unroll
    for (int f = 0; f < 16; ++f)
      bw[f] = *(const short8*)(wfrag + f * 512 + lane * 8);
    const ushort* ag = actg + (size_t)(base + c) * 64 + q * 8;  // row base+c, cols q*8..
    short8 a0 = *(const short8*)(ag);            // prefetch tile 0 (global)
    short8 a1 = *(const short8*)(ag + 32);
    for (int mt = 0; mt < 8; ++mt) {
      const short8 ca0 = a0, ca1 = a1;
      if (mt < 7) {                              // prefetch tile mt+1 (global, linear)
        const ushort* an = ag + (size_t)(mt + 1) * 16 * 64;
        a0 = *(const short8*)(an);
        a1 = *(const short8*)(an + 32);
      }
      f32x4 av[8];
#pragma unroll
      for (int t = 0; t < 8; ++t) av[t] = f32x4{0.f, 0.f, 0.f, 0.f};
#pragma unroll
      for (int t = 0; t < 8; ++t) {
        av[t] = MFMA(ca0, bw[t*2+0], av[t]);
        av[t] = MFMA(ca1, bw[t*2+1], av[t]);
      }
      asm volatile("s_waitcnt lgkmcnt(0)" ::: "memory");
      char* yb = act + (mt * 16 + q * 4) * ROWB + c * 2;
#pragma unroll
      for (int t = 0; t < 8; ++t)
#pragma unroll
        for (int r = 0; r < 4; ++r)
          *(ushort*)(yb + r * ROWB + t * 32) = (ushort)f2bf(fmaxf(av[t][r], 0.f));
    }
  }
  asm volatile("s_waitcnt lgkmcnt(0)" ::: "memory");

  // ======== hidden layers h0,h1 (relu->act) and h2 (+w_out dot, store) ========
  for (int l = 0; l < 3; ++l) {
    const ushort* wl = wfrag + WIN_ELTS + l * WH_ELTS;
    short8 bw[32];
#pragma unroll
    for (int f = 0; f < 32; ++f)
      bw[f] = *(const short8*)(wl + f * 512 + lane * 8);
    if (l < 2) {
      const char* ar0 = act + c * ROWB + q * 16;        // prefetch tile 0
      short8 a0 = *(const short8*)(ar0);
      short8 a1 = *(const short8*)(ar0 + 64);
      short8 a2 = *(const short8*)(ar0 + 128);
      short8 a3 = *(const short8*)(ar0 + 192);
      for (int mt = 0; mt < 8; ++mt) {
        const short8 ca0 = a0, ca1 = a1, ca2 = a2, ca3 = a3;
        if (mt < 7) {                                   // prefetch tile mt+1
          const char* arn = act + ((mt + 1) * 16 + c) * ROWB + q * 16;
          a0 = *(const short8*)(arn);
          a1 = *(const short8*)(arn + 64);
          a2 = *(const short8*)(arn + 128);
          a3 = *(const short8*)(arn + 192);
        }
        f32x4 av[8];
#pragma unroll
        for (int t = 0; t < 8; ++t) av[t] = f32x4{0.f, 0.f, 0.f, 0.f};
#pragma unroll
        for (int t = 0; t < 8; ++t) {
          av[t] = MFMA(ca0, bw[t*4+0], av[t]);
          av[t] = MFMA(ca1, bw[t*4+1], av[t]);
          av[t] = MFMA(ca2, bw[t*4+2], av[t]);
          av[t] = MFMA(ca3, bw[t*4+3], av[t]);
        }
        asm volatile("s_waitcnt lgkmcnt(0)" ::: "memory");
        char* yb = act + (mt * 16 + q * 4) * ROWB + c * 2;
#pragma unroll
        for (int t = 0; t < 8; ++t)
#pragma unroll
          for (int r = 0; r < 4; ++r)
            *(ushort*)(yb + r * ROWB + t * 32) = (ushort)f2bf(fmaxf(av[t][r], 0.f));
      }
      asm volatile("s_waitcnt lgkmcnt(0)" ::: "memory");
    } else {
      float wo[8];
#pragma unroll
      for (int t = 0; t < 8; ++t) wo[t] = wout[t * 16 + c];
      const char* ar0 = act + c * ROWB + q * 16;        // prefetch tile 0
      short8 a0 = *(const short8*)(ar0);
      short8 a1 = *(const short8*)(ar0 + 64);
      short8 a2 = *(const short8*)(ar0 + 128);
      short8 a3 = *(const short8*)(ar0 + 192);
      for (int mt = 0; mt < 8; ++mt) {
        const short8 ca0 = a0, ca1 = a1, ca2 = a2, ca3 = a3;
        if (mt < 7) {                                   // prefetch tile mt+1 (read-only layer)
          const char* arn = act + ((mt + 1) * 16 + c) * ROWB + q * 16;
          a0 = *(const short8*)(arn);
          a1 = *(const short8*)(arn + 64);
          a2 = *(const short8*)(arn + 128);
          a3 = *(const short8*)(arn + 192);
        }
        f32x4 av[8];
#pragma unroll
        for (int t = 0; t < 8; ++t) av[t] = f32x4{0.f, 0.f, 0.f, 0.f};
#pragma unroll
        for (int t = 0; t < 8; ++t) {
          av[t] = MFMA(ca0, bw[t*4+0], av[t]);
          av[t] = MFMA(ca1, bw[t*4+1], av[t]);
          av[t] = MFMA(ca2, bw[t*4+2], av[t]);
          av[t] = MFMA(ca3, bw[t*4+3], av[t]);
        }
#pragma unroll
        for (int r = 0; r < 4; ++r) {
          float y = 0.f;
#pragma unroll
          for (int t = 0; t < 8; ++t) y += fmaxf(av[t][r], 0.f) * wo[t];
          y += __shfl_xor(y, 1, 64);
          y += __shfl_xor(y, 2, 64);
          y += __shfl_xor(y, 4, 64);
          y += __shfl_xor(y, 8, 64);
          if (c == r) {
            int gpo = base + mt * 16 + q * 4 + r;
            if (gpo < NPTS) out[gpo] = y;   // VOL scale: *1 + 0
          }
        }
      }
    }
  }
}

extern "C" void kernel_launch(void* const* d_in, const int* in_sizes, int n_in,
                              void* d_out, int out_size, void* d_ws, size_t ws_size,
                              hipStream_t stream) {
  const float* x    = (const float*)d_in[0];
  const float* fg   = (const float*)d_in[1];
  const float* win  = (const float*)d_in[2];
  const float* wh0  = (const float*)d_in[3];
  const float* wh1  = (const float*)d_in[4];
  const float* wh2  = (const float*)d_in[5];
  const float* wout = (const float*)d_in[6];
  float* out = (float*)d_out;

  ushort* gridb = (ushort*)d_ws;                       // 28,311,552 B
  ushort* wfrag = (ushort*)d_ws + WFRAG_OFF;           // +114,688 B
  ushort* actg  = (ushort*)d_ws + ACT_OFF;             // +128,057,344 B staged rows

  k_grid_pack<<<GSP / 256, 256, 0, stream>>>(fg, gridb);
  k_w_pack<<<(WIN_ELTS + 3 * WH_ELTS) / 256, 256, 0, stream>>>(win, wh0, wh1, wh2, wfrag);
  k_gather<<<NROWS / 256, 256, 0, stream>>>(x, gridb, actg);

  const int nblk = (NPTS + 4 * PW - 1) / (4 * PW);     // 1954
  k_mlp<<<nblk, 256, LDS_BYTES, stream>>>(actg, wout, wfrag, out);
}

// Round 6
// 411.240 us; speedup vs baseline: 1.2459x; 1.2459x over previous
//
#include <hip/hip_runtime.h>
#include <stdint.h>

typedef unsigned int uint;
typedef unsigned short ushort;

#define GD   96
#define GD2  (GD*GD)           // 9216
#define GSP  (GD*GD*GD)        // 884736 spatial cells
#define NPTS 1000000
#define WIN_ELTS 8192          // padded w_in frags: 64x128
#define WH_ELTS  16384         // 128x128
#define WFRAG_OFF (GSP*16)     // ushort offset of weight frags in ws
#define WFRAG_N  (WIN_ELTS + 3*WH_ELTS)   // 57344 ushorts

#define NSLAB 8
#define SLABZ 12               // 96/8 z-planes per slab; slab table = 3.54 MB < 4 MB L2
#define CAP   131072           // slot capacity per slab = 256 blocks x 512
#define NSLOT (NSLAB*CAP)      // 1,048,576 total slots

// byte offsets in workspace
#define XS_BYTE   ((size_t)(WFRAG_OFF + WFRAG_N) * 2)         // 28,426,240 (16B aligned)
#define OID_BYTE  (XS_BYTE + (size_t)NSLOT * 16)              // + 16 MB
#define CUR_BYTE  (OID_BYTE + (size_t)NSLOT * 4)              // + 4 MB

#define PW   128               // points per wave (proven geometry)
#define ROWB 272               // LDS activation row stride bytes (136 bf16: 128 + 8 pad)
#define LDS_BYTES (4*PW*ROWB)  // 139264

typedef __attribute__((ext_vector_type(8))) short short8;
typedef __attribute__((ext_vector_type(4))) float f32x4;

__device__ __forceinline__ uint f2bf(float x) {           // fp32 -> bf16 (RNE)
  uint u = __float_as_uint(x);
  return (u + 0x7fffu + ((u >> 16) & 1u)) >> 16;
}

// ---- pre-pass 1: feature grid [C,D,H,W] f32 -> [D,H,W,C] bf16 ----
__global__ void k_grid_pack(const float* __restrict__ g, ushort* __restrict__ o) {
  int sp = blockIdx.x * 256 + threadIdx.x;   // 0..884735
  uint pk[8];
#pragma unroll
  for (int c = 0; c < 16; c += 2) {
    float a = g[(size_t)c * GSP + sp];
    float b = g[(size_t)(c + 1) * GSP + sp];
    pk[c >> 1] = f2bf(a) | (f2bf(b) << 16);
  }
  uint4* dst = (uint4*)(o + (size_t)sp * 16);
  dst[0] = make_uint4(pk[0], pk[1], pk[2], pk[3]);
  dst[1] = make_uint4(pk[4], pk[5], pk[6], pk[7]);
}

// ---- pre-pass 2: weights -> MFMA B-fragment-packed bf16 ----
__global__ void k_w_pack(const float* __restrict__ win, const float* __restrict__ h0,
                         const float* __restrict__ h1, const float* __restrict__ h2,
                         ushort* __restrict__ o) {
  int tid = blockIdx.x * 256 + threadIdx.x;  // < 57344
  int lane = (tid >> 3) & 63, j = tid & 7;
  int q = lane >> 4, cc = lane & 15;
  float v;
  if (tid < WIN_ELTS) {
    int blk = tid >> 9;
    int t = blk >> 1, s = blk & 1;
    int k = s * 32 + q * 8 + j, n = t * 16 + cc;
    v = (k < 52) ? win[k * 128 + n] : 0.f;
  } else {
    int f2 = tid - WIN_ELTS;
    int l = f2 >> 14, r = f2 & 16383;
    int blk = r >> 9;
    int t = blk >> 2, s = blk & 3;
    int k = s * 32 + q * 8 + j, n = t * 16 + cc;
    const float* w = (l == 0) ? h0 : ((l == 1) ? h1 : h2);
    v = w[k * 128 + n];
  }
  o[tid] = (ushort)f2bf(v);
}

// ---- pre-pass 3: fill all slots with pad point (NPTS-1), init cursors ----
__global__ void k_prefill(const float* __restrict__ x, float4* __restrict__ xs,
                          int* __restrict__ oid, int* __restrict__ cursor) {
  int id = blockIdx.x * 256 + threadIdx.x;   // 0..NSLOT-1
  float lx = x[(NPTS - 1) * 3 + 0];
  float ly = x[(NPTS - 1) * 3 + 1];
  float lz = x[(NPTS - 1) * 3 + 2];
  xs[id] = make_float4(lx, ly, lz, 0.f);
  oid[id] = NPTS - 1;
  if (id < NSLAB) cursor[id] = id * CAP;
}

// ---- pre-pass 4: bin points into z-slab slots (block-aggregated atomics) ----
__global__ void k_scatter(const float* __restrict__ x, float4* __restrict__ xs,
                          int* __restrict__ oid, int* __restrict__ cursor) {
  __shared__ int lc[NSLAB], lb[NSLAB];
  const int tid = threadIdx.x;
  if (tid < NSLAB) lc[tid] = 0;
  __syncthreads();
  const int pbase = blockIdx.x * 4096;
  int rk[16], sl[16];
#pragma unroll
  for (int i = 0; i < 16; ++i) {
    int p = pbase + i * 256 + tid;
    int pc = min(p, NPTS - 1);
    float pz = x[pc * 3 + 2];
    int z0i = min(max((int)floorf((pz + 1.0f) * 0.5f * 95.0f), 0), 95);
    int s = z0i / SLABZ;                     // 0..7
    sl[i] = s;
    rk[i] = (p < NPTS) ? atomicAdd(&lc[s], 1) : -1;
  }
  __syncthreads();
  if (tid < NSLAB) lb[tid] = atomicAdd(&cursor[tid], lc[tid]);
  __syncthreads();
#pragma unroll
  for (int i = 0; i < 16; ++i) {
    int p = pbase + i * 256 + tid;
    if (p < NPTS) {
      int slot = lb[sl[i]] + rk[i];
      xs[slot] = make_float4(x[p * 3 + 0], x[p * 3 + 1], x[p * 3 + 2], 0.f);
      oid[slot] = p;
    }
  }
}

#define ACC8(off, U, W) {                                  \
  fv[(off)+0] += (W) * __uint_as_float((U).x << 16);       \
  fv[(off)+1] += (W) * __uint_as_float((U).x & 0xffff0000u);\
  fv[(off)+2] += (W) * __uint_as_float((U).y << 16);       \
  fv[(off)+3] += (W) * __uint_as_float((U).y & 0xffff0000u);\
  fv[(off)+4] += (W) * __uint_as_float((U).z << 16);       \
  fv[(off)+5] += (W) * __uint_as_float((U).z & 0xffff0000u);\
  fv[(off)+6] += (W) * __uint_as_float((U).w << 16);       \
  fv[(off)+7] += (W) * __uint_as_float((U).w & 0xffff0000u);\
}

#define MFMA(A,B,C) __builtin_amdgcn_mfma_f32_16x16x32_bf16((A),(B),(C),0,0,0)

// ---- main fused kernel: 4 waves x 128 pts/wave; round-4 proven structure ----
// Block b handles slab s=b%8 (XCD-affine under round-robin dispatch), slots
// s*CAP + (b/8)*512 .. +512. MLP phases byte-identical to round-4.
__global__ __launch_bounds__(256, 1) void k_main(
    const float4* __restrict__ xs, const int* __restrict__ oid,
    const float* __restrict__ wout,
    const ushort* __restrict__ gridb, const ushort* __restrict__ wfrag,
    float* __restrict__ out) {
  extern __shared__ char smem[];
  const int wave = threadIdx.x >> 6;
  const int lane = threadIdx.x & 63;
  const int q = lane >> 4, c = lane & 15;
  char* act = smem + wave * (PW * ROWB);
  const int b = blockIdx.x;
  const int base = (b & 7) * CAP + (b >> 3) * 512 + wave * PW;   // slot base

  // ======== gather + positional encoding: 2 points per lane ========
#pragma unroll
  for (int pp = 0; pp < 2; ++pp) {
    const int p = pp * 64 + lane;
    const float4 c4 = xs[base + p];
    const float px = c4.x;
    const float py = c4.y;
    const float pz = c4.z;
    float fx = (px + 1.0f) * 0.5f * 95.0f;   // x -> W
    float fy = (py + 1.0f) * 0.5f * 95.0f;   // y -> H
    float fz = (pz + 1.0f) * 0.5f * 95.0f;   // z -> D
    float x0f = floorf(fx), y0f = floorf(fy), z0f = floorf(fz);
    float tx = fx - x0f, ty = fy - y0f, tz = fz - z0f;
    int x0i = min(max((int)x0f, 0), 95);
    int y0i = min(max((int)y0f, 0), 95);
    int z0i = min(max((int)z0f, 0), 95);
    int x1i = min(x0i + 1, 95);
    int y1i = min(y0i + 1, 95);
    int z1i = min(z0i + 1, 95);
    float fv[16];
#pragma unroll
    for (int k = 0; k < 16; ++k) fv[k] = 0.f;
#pragma unroll
    for (int dz = 0; dz < 2; ++dz) {
      const int zi = dz ? z1i : z0i;
      const float wz = dz ? tz : (1.f - tz);
#pragma unroll
      for (int dy = 0; dy < 2; ++dy) {
        const int yi = dy ? y1i : y0i;
        const float wzy = wz * (dy ? ty : (1.f - ty));
        const ushort* r0 = gridb + (size_t)(zi * GD2 + yi * GD + x0i) * 16;
        const ushort* r1 = gridb + (size_t)(zi * GD2 + yi * GD + x1i) * 16;
        uint4 a0 = *(const uint4*)r0;
        uint4 a1 = *(const uint4*)(r0 + 8);
        uint4 b0 = *(const uint4*)r1;
        uint4 b1 = *(const uint4*)(r1 + 8);
        const float w0 = wzy * (1.f - tx), w1 = wzy * tx;
        ACC8(0, a0, w0); ACC8(8, a1, w0);
        ACC8(0, b0, w1); ACC8(8, b1, w1);
      }
    }
    float row[64];
#pragma unroll
    for (int i = 0; i < 6; ++i) {
      const float fr = 3.14159265358979323846f * (float)(1 << i);
      row[i*6+0] = __sinf(px*fr); row[i*6+1] = __sinf(py*fr); row[i*6+2] = __sinf(pz*fr);
      row[i*6+3] = __cosf(px*fr); row[i*6+4] = __cosf(py*fr); row[i*6+5] = __cosf(pz*fr);
    }
#pragma unroll
    for (int k = 0; k < 16; ++k) row[36 + k] = fv[k];
#pragma unroll
    for (int k = 52; k < 64; ++k) row[k] = 0.f;
    char* dst = act + p * ROWB;
#pragma unroll
    for (int k = 0; k < 64; k += 8) {
      uint u0 = f2bf(row[k+0]) | (f2bf(row[k+1]) << 16);
      uint u1 = f2bf(row[k+2]) | (f2bf(row[k+3]) << 16);
      uint u2 = f2bf(row[k+4]) | (f2bf(row[k+5]) << 16);
      uint u3 = f2bf(row[k+6]) | (f2bf(row[k+7]) << 16);
      *(uint4*)(dst + k * 2) = make_uint4(u0, u1, u2, u3);
    }
  }
  asm volatile("s_waitcnt lgkmcnt(0)" ::: "memory");

  // ======== layer-in: X[128x64] @ w_in[64x128] -> relu -> act ========
  {
    short8 bw[16];
#pragma unroll
    for (int f = 0; f < 16; ++f)
      bw[f] = *(const short8*)(wfrag + f * 512 + lane * 8);
    const char* ar0 = act + c * ROWB + q * 16;          // prefetch tile 0
    short8 a0 = *(const short8*)(ar0);
    short8 a1 = *(const short8*)(ar0 + 64);
    for (int mt = 0; mt < 8; ++mt) {
      const short8 ca0 = a0, ca1 = a1;
      if (mt < 7) {                                     // prefetch tile mt+1
        const char* arn = act + ((mt + 1) * 16 + c) * ROWB + q * 16;
        a0 = *(const short8*)(arn);
        a1 = *(const short8*)(arn + 64);
      }
      f32x4 av[8];
#pragma unroll
      for (int t = 0; t < 8; ++t) av[t] = f32x4{0.f, 0.f, 0.f, 0.f};
#pragma unroll
      for (int t = 0; t < 8; ++t) {
        av[t] = MFMA(ca0, bw[t*2+0], av[t]);
        av[t] = MFMA(ca1, bw[t*2+1], av[t]);
      }
      asm volatile("s_waitcnt lgkmcnt(0)" ::: "memory");
      char* yb = act + (mt * 16 + q * 4) * ROWB + c * 2;
#pragma unroll
      for (int t = 0; t < 8; ++t)
#pragma unroll
        for (int r = 0; r < 4; ++r)
          *(ushort*)(yb + r * ROWB + t * 32) = (ushort)f2bf(fmaxf(av[t][r], 0.f));
    }
  }
  asm volatile("s_waitcnt lgkmcnt(0)" ::: "memory");

  // ======== hidden layers h0,h1 (relu->act) and h2 (+w_out dot, store) ========
  for (int l = 0; l < 3; ++l) {
    const ushort* wl = wfrag + WIN_ELTS + l * WH_ELTS;
    short8 bw[32];
#pragma unroll
    for (int f = 0; f < 32; ++f)
      bw[f] = *(const short8*)(wl + f * 512 + lane * 8);
    if (l < 2) {
      const char* ar0 = act + c * ROWB + q * 16;        // prefetch tile 0
      short8 a0 = *(const short8*)(ar0);
      short8 a1 = *(const short8*)(ar0 + 64);
      short8 a2 = *(const short8*)(ar0 + 128);
      short8 a3 = *(const short8*)(ar0 + 192);
      for (int mt = 0; mt < 8; ++mt) {
        const short8 ca0 = a0, ca1 = a1, ca2 = a2, ca3 = a3;
        if (mt < 7) {                                   // prefetch tile mt+1
          const char* arn = act + ((mt + 1) * 16 + c) * ROWB + q * 16;
          a0 = *(const short8*)(arn);
          a1 = *(const short8*)(arn + 64);
          a2 = *(const short8*)(arn + 128);
          a3 = *(const short8*)(arn + 192);
        }
        f32x4 av[8];
#pragma unroll
        for (int t = 0; t < 8; ++t) av[t] = f32x4{0.f, 0.f, 0.f, 0.f};
#pragma unroll
        for (int t = 0; t < 8; ++t) {
          av[t] = MFMA(ca0, bw[t*4+0], av[t]);
          av[t] = MFMA(ca1, bw[t*4+1], av[t]);
          av[t] = MFMA(ca2, bw[t*4+2], av[t]);
          av[t] = MFMA(ca3, bw[t*4+3], av[t]);
        }
        asm volatile("s_waitcnt lgkmcnt(0)" ::: "memory");
        char* yb = act + (mt * 16 + q * 4) * ROWB + c * 2;
#pragma unroll
        for (int t = 0; t < 8; ++t)
#pragma unroll
          for (int r = 0; r < 4; ++r)
            *(ushort*)(yb + r * ROWB + t * 32) = (ushort)f2bf(fmaxf(av[t][r], 0.f));
      }
      asm volatile("s_waitcnt lgkmcnt(0)" ::: "memory");
    } else {
      float wo[8];
#pragma unroll
      for (int t = 0; t < 8; ++t) wo[t] = wout[t * 16 + c];
      const char* ar0 = act + c * ROWB + q * 16;        // prefetch tile 0
      short8 a0 = *(const short8*)(ar0);
      short8 a1 = *(const short8*)(ar0 + 64);
      short8 a2 = *(const short8*)(ar0 + 128);
      short8 a3 = *(const short8*)(ar0 + 192);
      for (int mt = 0; mt < 8; ++mt) {
        const short8 ca0 = a0, ca1 = a1, ca2 = a2, ca3 = a3;
        if (mt < 7) {                                   // prefetch tile mt+1 (read-only layer)
          const char* arn = act + ((mt + 1) * 16 + c) * ROWB + q * 16;
          a0 = *(const short8*)(arn);
          a1 = *(const short8*)(arn + 64);
          a2 = *(const short8*)(arn + 128);
          a3 = *(const short8*)(arn + 192);
        }
        f32x4 av[8];
#pragma unroll
        for (int t = 0; t < 8; ++t) av[t] = f32x4{0.f, 0.f, 0.f, 0.f};
#pragma unroll
        for (int t = 0; t < 8; ++t) {
          av[t] = MFMA(ca0, bw[t*4+0], av[t]);
          av[t] = MFMA(ca1, bw[t*4+1], av[t]);
          av[t] = MFMA(ca2, bw[t*4+2], av[t]);
          av[t] = MFMA(ca3, bw[t*4+3], av[t]);
        }
#pragma unroll
        for (int r = 0; r < 4; ++r) {
          float y = 0.f;
#pragma unroll
          for (int t = 0; t < 8; ++t) y += fmaxf(av[t][r], 0.f) * wo[t];
          y += __shfl_xor(y, 1, 64);
          y += __shfl_xor(y, 2, 64);
          y += __shfl_xor(y, 4, 64);
          y += __shfl_xor(y, 8, 64);
          if (c == r) {
            int slot = base + mt * 16 + q * 4 + r;
            out[oid[slot]] = y;   // pad slots dup point NPTS-1: same value, benign
          }
        }
      }
    }
  }
}

extern "C" void kernel_launch(void* const* d_in, const int* in_sizes, int n_in,
                              void* d_out, int out_size, void* d_ws, size_t ws_size,
                              hipStream_t stream) {
  const float* x    = (const float*)d_in[0];
  const float* fg   = (const float*)d_in[1];
  const float* win  = (const float*)d_in[2];
  const float* wh0  = (const float*)d_in[3];
  const float* wh1  = (const float*)d_in[4];
  const float* wh2  = (const float*)d_in[5];
  const float* wout = (const float*)d_in[6];
  float* out = (float*)d_out;

  char* wsb = (char*)d_ws;
  ushort* gridb  = (ushort*)d_ws;                      // 28,311,552 B
  ushort* wfrag  = (ushort*)d_ws + WFRAG_OFF;          // +114,688 B
  float4* xs     = (float4*)(wsb + XS_BYTE);           // 16.8 MB
  int*    oid    = (int*)(wsb + OID_BYTE);             // 4.2 MB
  int*    cursor = (int*)(wsb + CUR_BYTE);             // 32 B

  k_grid_pack<<<GSP / 256, 256, 0, stream>>>(fg, gridb);
  k_w_pack<<<(WIN_ELTS + 3 * WH_ELTS) / 256, 256, 0, stream>>>(win, wh0, wh1, wh2, wfrag);
  k_prefill<<<NSLOT / 256, 256, 0, stream>>>(x, xs, oid, cursor);
  k_scatter<<<(NPTS + 4095) / 4096, 256, 0, stream>>>(x, xs, oid, cursor);

  k_main<<<NSLAB * (CAP / 512), 256, LDS_BYTES, stream>>>(xs, oid, wout, gridb, wfrag, out);
}

// Round 8
// 390.469 us; speedup vs baseline: 1.3122x; 1.0532x over previous
//
#include <hip/hip_runtime.h>
#include <stdint.h>

typedef unsigned int uint;
typedef unsigned short ushort;

#define GD   96
#define GD2  (GD*GD)           // 9216
#define GSP  (GD*GD*GD)        // 884736 spatial cells
#define NPTS 1000000
#define WIN_ELTS 8192          // padded w_in frags: 64x128
#define WH_ELTS  16384         // 128x128
#define WFRAG_OFF (GSP*16)     // ushort offset of weight frags in ws
#define WFRAG_N  (WIN_ELTS + 3*WH_ELTS)   // 57344 ushorts

#define NSLAB 8
#define SLABZ 12               // 96/8 z-planes per slab; slab table = 3.54 MB < 4 MB L2
#define CAP   131072           // slot capacity per slab = 256 blocks x 512
#define NSLOT (NSLAB*CAP)      // 1,048,576 total slots

// byte offsets in workspace
#define XS_BYTE   ((size_t)(WFRAG_OFF + WFRAG_N) * 2)         // 28,426,240 (16B aligned)
#define OID_BYTE  (XS_BYTE + (size_t)NSLOT * 16)              // + 16 MB
#define CUR_BYTE  (OID_BYTE + (size_t)NSLOT * 4)              // + 4 MB

#define PW   128               // points per wave (proven geometry — PW=64 is cursed, closed)
#define ROWB 272               // LDS activation row stride bytes (136 bf16: 128 + 8 pad)
#define LDS_BYTES (4*PW*ROWB)  // 139264

typedef __attribute__((ext_vector_type(8))) short short8;
typedef __attribute__((ext_vector_type(4))) float f32x4;

__device__ __forceinline__ uint f2bf(float x) {           // fp32 -> bf16 (RNE)
  uint u = __float_as_uint(x);
  return (u + 0x7fffu + ((u >> 16) & 1u)) >> 16;
}

// ---- pre-pass 1: feature grid [C,D,H,W] f32 -> [D,H,W,C] bf16 ----
__global__ void k_grid_pack(const float* __restrict__ g, ushort* __restrict__ o) {
  int sp = blockIdx.x * 256 + threadIdx.x;   // 0..884735
  uint pk[8];
#pragma unroll
  for (int c = 0; c < 16; c += 2) {
    float a = g[(size_t)c * GSP + sp];
    float b = g[(size_t)(c + 1) * GSP + sp];
    pk[c >> 1] = f2bf(a) | (f2bf(b) << 16);
  }
  uint4* dst = (uint4*)(o + (size_t)sp * 16);
  dst[0] = make_uint4(pk[0], pk[1], pk[2], pk[3]);
  dst[1] = make_uint4(pk[4], pk[5], pk[6], pk[7]);
}

// ---- pre-pass 2: weights -> MFMA B-fragment-packed bf16 ----
__global__ void k_w_pack(const float* __restrict__ win, const float* __restrict__ h0,
                         const float* __restrict__ h1, const float* __restrict__ h2,
                         ushort* __restrict__ o) {
  int tid = blockIdx.x * 256 + threadIdx.x;  // < 57344
  int lane = (tid >> 3) & 63, j = tid & 7;
  int q = lane >> 4, cc = lane & 15;
  float v;
  if (tid < WIN_ELTS) {
    int blk = tid >> 9;
    int t = blk >> 1, s = blk & 1;
    int k = s * 32 + q * 8 + j, n = t * 16 + cc;
    v = (k < 52) ? win[k * 128 + n] : 0.f;
  } else {
    int f2 = tid - WIN_ELTS;
    int l = f2 >> 14, r = f2 & 16383;
    int blk = r >> 9;
    int t = blk >> 2, s = blk & 3;
    int k = s * 32 + q * 8 + j, n = t * 16 + cc;
    const float* w = (l == 0) ? h0 : ((l == 1) ? h1 : h2);
    v = w[k * 128 + n];
  }
  o[tid] = (ushort)f2bf(v);
}

// ---- pre-pass 3: fill all slots with pad point (NPTS-1), init cursors ----
__global__ void k_prefill(const float* __restrict__ x, float4* __restrict__ xs,
                          int* __restrict__ oid, int* __restrict__ cursor) {
  int id = blockIdx.x * 256 + threadIdx.x;   // 0..NSLOT-1
  float lx = x[(NPTS - 1) * 3 + 0];
  float ly = x[(NPTS - 1) * 3 + 1];
  float lz = x[(NPTS - 1) * 3 + 2];
  xs[id] = make_float4(lx, ly, lz, 0.f);
  oid[id] = NPTS - 1;
  if (id < NSLAB) cursor[id] = id * CAP;
}

// ---- pre-pass 4: bin points into z-slab slots (block-aggregated atomics) ----
__global__ void k_scatter(const float* __restrict__ x, float4* __restrict__ xs,
                          int* __restrict__ oid, int* __restrict__ cursor) {
  __shared__ int lc[NSLAB], lb[NSLAB];
  const int tid = threadIdx.x;
  if (tid < NSLAB) lc[tid] = 0;
  __syncthreads();
  const int pbase = blockIdx.x * 4096;
  int rk[16], sl[16];
#pragma unroll
  for (int i = 0; i < 16; ++i) {
    int p = pbase + i * 256 + tid;
    int pc = min(p, NPTS - 1);
    float pz = x[pc * 3 + 2];
    int z0i = min(max((int)floorf((pz + 1.0f) * 0.5f * 95.0f), 0), 95);
    int s = z0i / SLABZ;                     // 0..7
    sl[i] = s;
    rk[i] = (p < NPTS) ? atomicAdd(&lc[s], 1) : -1;
  }
  __syncthreads();
  if (tid < NSLAB) lb[tid] = atomicAdd(&cursor[tid], lc[tid]);
  __syncthreads();
#pragma unroll
  for (int i = 0; i < 16; ++i) {
    int p = pbase + i * 256 + tid;
    if (p < NPTS) {
      int slot = lb[sl[i]] + rk[i];
      xs[slot] = make_float4(x[p * 3 + 0], x[p * 3 + 1], x[p * 3 + 2], 0.f);
      oid[slot] = p;
    }
  }
}

#define ACC8(off, U, W) {                                  \
  fv[(off)+0] += (W) * __uint_as_float((U).x << 16);       \
  fv[(off)+1] += (W) * __uint_as_float((U).x & 0xffff0000u);\
  fv[(off)+2] += (W) * __uint_as_float((U).y << 16);       \
  fv[(off)+3] += (W) * __uint_as_float((U).y & 0xffff0000u);\
  fv[(off)+4] += (W) * __uint_as_float((U).z << 16);       \
  fv[(off)+5] += (W) * __uint_as_float((U).z & 0xffff0000u);\
  fv[(off)+6] += (W) * __uint_as_float((U).w << 16);       \
  fv[(off)+7] += (W) * __uint_as_float((U).w & 0xffff0000u);\
}

#define MFMA(A,B,C) __builtin_amdgcn_mfma_f32_16x16x32_bf16((A),(B),(C),0,0,0)

// ---- main fused kernel: 4 waves x 128 pts/wave; slab-affine slots ----
// Change vs r6 green: 2-tile batching in all matmul phases — both tiles'
// A-frag reads issued before MFMAs, both epilogues after one fence. Halves
// serial tile boundaries; 16 independent MFMA chains per pair.
__global__ __launch_bounds__(256, 1) void k_main(
    const float4* __restrict__ xs, const int* __restrict__ oid,
    const float* __restrict__ wout,
    const ushort* __restrict__ gridb, const ushort* __restrict__ wfrag,
    float* __restrict__ out) {
  extern __shared__ char smem[];
  const int wave = threadIdx.x >> 6;
  const int lane = threadIdx.x & 63;
  const int q = lane >> 4, c = lane & 15;
  char* act = smem + wave * (PW * ROWB);
  const int b = blockIdx.x;
  const int base = (b & 7) * CAP + (b >> 3) * 512 + wave * PW;   // slot base

  // ======== gather + positional encoding: 2 points per lane ========
#pragma unroll
  for (int pp = 0; pp < 2; ++pp) {
    const int p = pp * 64 + lane;
    const float4 c4 = xs[base + p];
    const float px = c4.x;
    const float py = c4.y;
    const float pz = c4.z;
    float fx = (px + 1.0f) * 0.5f * 95.0f;   // x -> W
    float fy = (py + 1.0f) * 0.5f * 95.0f;   // y -> H
    float fz = (pz + 1.0f) * 0.5f * 95.0f;   // z -> D
    float x0f = floorf(fx), y0f = floorf(fy), z0f = floorf(fz);
    float tx = fx - x0f, ty = fy - y0f, tz = fz - z0f;
    int x0i = min(max((int)x0f, 0), 95);
    int y0i = min(max((int)y0f, 0), 95);
    int z0i = min(max((int)z0f, 0), 95);
    int x1i = min(x0i + 1, 95);
    int y1i = min(y0i + 1, 95);
    int z1i = min(z0i + 1, 95);
    float fv[16];
#pragma unroll
    for (int k = 0; k < 16; ++k) fv[k] = 0.f;
#pragma unroll
    for (int dz = 0; dz < 2; ++dz) {
      const int zi = dz ? z1i : z0i;
      const float wz = dz ? tz : (1.f - tz);
#pragma unroll
      for (int dy = 0; dy < 2; ++dy) {
        const int yi = dy ? y1i : y0i;
        const float wzy = wz * (dy ? ty : (1.f - ty));
        const ushort* r0 = gridb + (size_t)(zi * GD2 + yi * GD + x0i) * 16;
        const ushort* r1 = gridb + (size_t)(zi * GD2 + yi * GD + x1i) * 16;
        uint4 a0 = *(const uint4*)r0;
        uint4 a1 = *(const uint4*)(r0 + 8);
        uint4 b0 = *(const uint4*)r1;
        uint4 b1 = *(const uint4*)(r1 + 8);
        const float w0 = wzy * (1.f - tx), w1 = wzy * tx;
        ACC8(0, a0, w0); ACC8(8, a1, w0);
        ACC8(0, b0, w1); ACC8(8, b1, w1);
      }
    }
    float row[64];
#pragma unroll
    for (int i = 0; i < 6; ++i) {
      const float fr = 3.14159265358979323846f * (float)(1 << i);
      row[i*6+0] = __sinf(px*fr); row[i*6+1] = __sinf(py*fr); row[i*6+2] = __sinf(pz*fr);
      row[i*6+3] = __cosf(px*fr); row[i*6+4] = __cosf(py*fr); row[i*6+5] = __cosf(pz*fr);
    }
#pragma unroll
    for (int k = 0; k < 16; ++k) row[36 + k] = fv[k];
#pragma unroll
    for (int k = 52; k < 64; ++k) row[k] = 0.f;
    char* dst = act + p * ROWB;
#pragma unroll
    for (int k = 0; k < 64; k += 8) {
      uint u0 = f2bf(row[k+0]) | (f2bf(row[k+1]) << 16);
      uint u1 = f2bf(row[k+2]) | (f2bf(row[k+3]) << 16);
      uint u2 = f2bf(row[k+4]) | (f2bf(row[k+5]) << 16);
      uint u3 = f2bf(row[k+6]) | (f2bf(row[k+7]) << 16);
      *(uint4*)(dst + k * 2) = make_uint4(u0, u1, u2, u3);
    }
  }
  asm volatile("s_waitcnt lgkmcnt(0)" ::: "memory");

  // ======== layer-in: X[128x64] @ w_in[64x128] -> relu -> act ========
  {
    short8 bw[16];
#pragma unroll
    for (int f = 0; f < 16; ++f)
      bw[f] = *(const short8*)(wfrag + f * 512 + lane * 8);
    for (int mt = 0; mt < 8; mt += 2) {
      const char* arA = act + (mt * 16 + c) * ROWB + q * 16;
      const char* arB = arA + 16 * ROWB;
      short8 aA0 = *(const short8*)(arA);
      short8 aA1 = *(const short8*)(arA + 64);
      short8 aB0 = *(const short8*)(arB);
      short8 aB1 = *(const short8*)(arB + 64);
      f32x4 avA[8], avB[8];
#pragma unroll
      for (int t = 0; t < 8; ++t) { avA[t] = f32x4{0.f,0.f,0.f,0.f}; avB[t] = f32x4{0.f,0.f,0.f,0.f}; }
#pragma unroll
      for (int t = 0; t < 8; ++t) {
        avA[t] = MFMA(aA0, bw[t*2+0], avA[t]);
        avA[t] = MFMA(aA1, bw[t*2+1], avA[t]);
        avB[t] = MFMA(aB0, bw[t*2+0], avB[t]);
        avB[t] = MFMA(aB1, bw[t*2+1], avB[t]);
      }
      asm volatile("s_waitcnt lgkmcnt(0)" ::: "memory");
      char* ybA = act + (mt * 16 + q * 4) * ROWB + c * 2;
      char* ybB = ybA + 16 * ROWB;
#pragma unroll
      for (int t = 0; t < 8; ++t)
#pragma unroll
        for (int r = 0; r < 4; ++r) {
          *(ushort*)(ybA + r * ROWB + t * 32) = (ushort)f2bf(fmaxf(avA[t][r], 0.f));
          *(ushort*)(ybB + r * ROWB + t * 32) = (ushort)f2bf(fmaxf(avB[t][r], 0.f));
        }
    }
  }
  asm volatile("s_waitcnt lgkmcnt(0)" ::: "memory");

  // ======== hidden layers h0,h1 (relu->act) and h2 (+w_out dot, store) ========
  for (int l = 0; l < 3; ++l) {
    const ushort* wl = wfrag + WIN_ELTS + l * WH_ELTS;
    short8 bw[32];
#pragma unroll
    for (int f = 0; f < 32; ++f)
      bw[f] = *(const short8*)(wl + f * 512 + lane * 8);
    if (l < 2) {
      for (int mt = 0; mt < 8; mt += 2) {
        const char* arA = act + (mt * 16 + c) * ROWB + q * 16;
        const char* arB = arA + 16 * ROWB;
        short8 aA0 = *(const short8*)(arA);
        short8 aA1 = *(const short8*)(arA + 64);
        short8 aA2 = *(const short8*)(arA + 128);
        short8 aA3 = *(const short8*)(arA + 192);
        short8 aB0 = *(const short8*)(arB);
        short8 aB1 = *(const short8*)(arB + 64);
        short8 aB2 = *(const short8*)(arB + 128);
        short8 aB3 = *(const short8*)(arB + 192);
        f32x4 avA[8], avB[8];
#pragma unroll
        for (int t = 0; t < 8; ++t) { avA[t] = f32x4{0.f,0.f,0.f,0.f}; avB[t] = f32x4{0.f,0.f,0.f,0.f}; }
#pragma unroll
        for (int t = 0; t < 8; ++t) {
          avA[t] = MFMA(aA0, bw[t*4+0], avA[t]);
          avA[t] = MFMA(aA1, bw[t*4+1], avA[t]);
          avA[t] = MFMA(aA2, bw[t*4+2], avA[t]);
          avA[t] = MFMA(aA3, bw[t*4+3], avA[t]);
          avB[t] = MFMA(aB0, bw[t*4+0], avB[t]);
          avB[t] = MFMA(aB1, bw[t*4+1], avB[t]);
          avB[t] = MFMA(aB2, bw[t*4+2], avB[t]);
          avB[t] = MFMA(aB3, bw[t*4+3], avB[t]);
        }
        asm volatile("s_waitcnt lgkmcnt(0)" ::: "memory");
        char* ybA = act + (mt * 16 + q * 4) * ROWB + c * 2;
        char* ybB = ybA + 16 * ROWB;
#pragma unroll
        for (int t = 0; t < 8; ++t)
#pragma unroll
          for (int r = 0; r < 4; ++r) {
            *(ushort*)(ybA + r * ROWB + t * 32) = (ushort)f2bf(fmaxf(avA[t][r], 0.f));
            *(ushort*)(ybB + r * ROWB + t * 32) = (ushort)f2bf(fmaxf(avB[t][r], 0.f));
          }
      }
      asm volatile("s_waitcnt lgkmcnt(0)" ::: "memory");
    } else {
      float wo[8];
#pragma unroll
      for (int t = 0; t < 8; ++t) wo[t] = wout[t * 16 + c];
      for (int mt = 0; mt < 8; mt += 2) {
        const char* arA = act + (mt * 16 + c) * ROWB + q * 16;
        const char* arB = arA + 16 * ROWB;
        short8 aA0 = *(const short8*)(arA);
        short8 aA1 = *(const short8*)(arA + 64);
        short8 aA2 = *(const short8*)(arA + 128);
        short8 aA3 = *(const short8*)(arA + 192);
        short8 aB0 = *(const short8*)(arB);
        short8 aB1 = *(const short8*)(arB + 64);
        short8 aB2 = *(const short8*)(arB + 128);
        short8 aB3 = *(const short8*)(arB + 192);
        f32x4 avA[8], avB[8];
#pragma unroll
        for (int t = 0; t < 8; ++t) { avA[t] = f32x4{0.f,0.f,0.f,0.f}; avB[t] = f32x4{0.f,0.f,0.f,0.f}; }
#pragma unroll
        for (int t = 0; t < 8; ++t) {
          avA[t] = MFMA(aA0, bw[t*4+0], avA[t]);
          avA[t] = MFMA(aA1, bw[t*4+1], avA[t]);
          avA[t] = MFMA(aA2, bw[t*4+2], avA[t]);
          avA[t] = MFMA(aA3, bw[t*4+3], avA[t]);
          avB[t] = MFMA(aB0, bw[t*4+0], avB[t]);
          avB[t] = MFMA(aB1, bw[t*4+1], avB[t]);
          avB[t] = MFMA(aB2, bw[t*4+2], avB[t]);
          avB[t] = MFMA(aB3, bw[t*4+3], avB[t]);
        }
#pragma unroll
        for (int r = 0; r < 4; ++r) {
          float yA = 0.f, yB = 0.f;
#pragma unroll
          for (int t = 0; t < 8; ++t) {
            yA += fmaxf(avA[t][r], 0.f) * wo[t];
            yB += fmaxf(avB[t][r], 0.f) * wo[t];
          }
          yA += __shfl_xor(yA, 1, 64);
          yA += __shfl_xor(yA, 2, 64);
          yA += __shfl_xor(yA, 4, 64);
          yA += __shfl_xor(yA, 8, 64);
          yB += __shfl_xor(yB, 1, 64);
          yB += __shfl_xor(yB, 2, 64);
          yB += __shfl_xor(yB, 4, 64);
          yB += __shfl_xor(yB, 8, 64);
          if (c == r) {
            int slotA = base + mt * 16 + q * 4 + r;
            out[oid[slotA]] = yA;   // pad slots dup point NPTS-1: same value, benign
            int slotB = slotA + 16;
            out[oid[slotB]] = yB;
          }
        }
      }
    }
  }
}

extern "C" void kernel_launch(void* const* d_in, const int* in_sizes, int n_in,
                              void* d_out, int out_size, void* d_ws, size_t ws_size,
                              hipStream_t stream) {
  const float* x    = (const float*)d_in[0];
  const float* fg   = (const float*)d_in[1];
  const float* win  = (const float*)d_in[2];
  const float* wh0  = (const float*)d_in[3];
  const float* wh1  = (const float*)d_in[4];
  const float* wh2  = (const float*)d_in[5];
  const float* wout = (const float*)d_in[6];
  float* out = (float*)d_out;

  char* wsb = (char*)d_ws;
  ushort* gridb  = (ushort*)d_ws;                      // 28,311,552 B
  ushort* wfrag  = (ushort*)d_ws + WFRAG_OFF;          // +114,688 B
  float4* xs     = (float4*)(wsb + XS_BYTE);           // 16.8 MB
  int*    oid    = (int*)(wsb + OID_BYTE);             // 4.2 MB
  int*    cursor = (int*)(wsb + CUR_BYTE);             // 32 B

  k_grid_pack<<<GSP / 256, 256, 0, stream>>>(fg, gridb);
  k_w_pack<<<(WIN_ELTS + 3 * WH_ELTS) / 256, 256, 0, stream>>>(win, wh0, wh1, wh2, wfrag);
  k_prefill<<<NSLOT / 256, 256, 0, stream>>>(x, xs, oid, cursor);
  k_scatter<<<(NPTS + 4095) / 4096, 256, 0, stream>>>(x, xs, oid, cursor);

  k_main<<<NSLAB * (CAP / 512), 256, LDS_BYTES, stream>>>(xs, oid, wout, gridb, wfrag, out);
}

// Round 10
// 386.263 us; speedup vs baseline: 1.3265x; 1.0109x over previous
//
#include <hip/hip_runtime.h>
#include <stdint.h>

typedef unsigned int uint;
typedef unsigned short ushort;

#define GD   96
#define GD2  (GD*GD)           // 9216
#define GSP  (GD*GD*GD)        // 884736 spatial cells
#define NPTS 1000000
#define WIN_ELTS 8192          // padded w_in frags: 64x128
#define WH_ELTS  16384         // 128x128
#define WFRAG_OFF (GSP*16)     // ushort offset of weight frags in ws
#define WFRAG_N  (WIN_ELTS + 3*WH_ELTS)   // 57344 ushorts

#define NSLAB 8
#define SLABZ 12               // 96/8 z-planes per slab; slab table = 3.54 MB < 4 MB L2
#define CAP   131072           // slot capacity per slab = 256 blocks x 512
#define NSLOT (NSLAB*CAP)      // 1,048,576 total slots

// byte offsets in workspace
#define XS_BYTE   ((size_t)(WFRAG_OFF + WFRAG_N) * 2)         // 28,426,240 (16B aligned)
#define OID_BYTE  (XS_BYTE + (size_t)NSLOT * 16)              // + 16 MB
#define CUR_BYTE  (OID_BYTE + (size_t)NSLOT * 4)              // + 4 MB

#define PW   128               // points per wave (proven geometry — PW=64 is cursed, closed)
#define ROWB 272               // LDS activation row stride bytes (136 bf16: 128 + 8 pad)
#define LDS_BYTES (4*PW*ROWB)  // 139264

typedef __attribute__((ext_vector_type(8))) short short8;
typedef __attribute__((ext_vector_type(4))) float f32x4;

__device__ __forceinline__ uint f2bf(float x) {           // fp32 -> bf16 (RNE)
  uint u = __float_as_uint(x);
  return (u + 0x7fffu + ((u >> 16) & 1u)) >> 16;
}

// ---- pre-pass 1: feature grid [C,D,H,W] f32 -> [D,H,W,C] bf16 ----
__global__ void k_grid_pack(const float* __restrict__ g, ushort* __restrict__ o) {
  int sp = blockIdx.x * 256 + threadIdx.x;   // 0..884735
  uint pk[8];
#pragma unroll
  for (int c = 0; c < 16; c += 2) {
    float a = g[(size_t)c * GSP + sp];
    float b = g[(size_t)(c + 1) * GSP + sp];
    pk[c >> 1] = f2bf(a) | (f2bf(b) << 16);
  }
  uint4* dst = (uint4*)(o + (size_t)sp * 16);
  dst[0] = make_uint4(pk[0], pk[1], pk[2], pk[3]);
  dst[1] = make_uint4(pk[4], pk[5], pk[6], pk[7]);
}

// ---- pre-pass 2: weights -> MFMA B-fragment-packed bf16 ----
__global__ void k_w_pack(const float* __restrict__ win, const float* __restrict__ h0,
                         const float* __restrict__ h1, const float* __restrict__ h2,
                         ushort* __restrict__ o) {
  int tid = blockIdx.x * 256 + threadIdx.x;  // < 57344
  int lane = (tid >> 3) & 63, j = tid & 7;
  int q = lane >> 4, cc = lane & 15;
  float v;
  if (tid < WIN_ELTS) {
    int blk = tid >> 9;
    int t = blk >> 1, s = blk & 1;
    int k = s * 32 + q * 8 + j, n = t * 16 + cc;
    v = (k < 52) ? win[k * 128 + n] : 0.f;
  } else {
    int f2 = tid - WIN_ELTS;
    int l = f2 >> 14, r = f2 & 16383;
    int blk = r >> 9;
    int t = blk >> 2, s = blk & 3;
    int k = s * 32 + q * 8 + j, n = t * 16 + cc;
    const float* w = (l == 0) ? h0 : ((l == 1) ? h1 : h2);
    v = w[k * 128 + n];
  }
  o[tid] = (ushort)f2bf(v);
}

// ---- pre-pass 3: fill all slots with pad point (NPTS-1), init cursors ----
__global__ void k_prefill(const float* __restrict__ x, float4* __restrict__ xs,
                          int* __restrict__ oid, int* __restrict__ cursor) {
  int id = blockIdx.x * 256 + threadIdx.x;   // 0..NSLOT-1
  float lx = x[(NPTS - 1) * 3 + 0];
  float ly = x[(NPTS - 1) * 3 + 1];
  float lz = x[(NPTS - 1) * 3 + 2];
  xs[id] = make_float4(lx, ly, lz, 0.f);
  oid[id] = NPTS - 1;
  if (id < NSLAB) cursor[id] = id * CAP;
}

// ---- pre-pass 4: bin points into z-slab slots (block-aggregated atomics) ----
__global__ void k_scatter(const float* __restrict__ x, float4* __restrict__ xs,
                          int* __restrict__ oid, int* __restrict__ cursor) {
  __shared__ int lc[NSLAB], lb[NSLAB];
  const int tid = threadIdx.x;
  if (tid < NSLAB) lc[tid] = 0;
  __syncthreads();
  const int pbase = blockIdx.x * 4096;
  int rk[16], sl[16];
#pragma unroll
  for (int i = 0; i < 16; ++i) {
    int p = pbase + i * 256 + tid;
    int pc = min(p, NPTS - 1);
    float pz = x[pc * 3 + 2];
    int z0i = min(max((int)floorf((pz + 1.0f) * 0.5f * 95.0f), 0), 95);
    int s = z0i / SLABZ;                     // 0..7
    sl[i] = s;
    rk[i] = (p < NPTS) ? atomicAdd(&lc[s], 1) : -1;
  }
  __syncthreads();
  if (tid < NSLAB) lb[tid] = atomicAdd(&cursor[tid], lc[tid]);
  __syncthreads();
#pragma unroll
  for (int i = 0; i < 16; ++i) {
    int p = pbase + i * 256 + tid;
    if (p < NPTS) {
      int slot = lb[sl[i]] + rk[i];
      xs[slot] = make_float4(x[p * 3 + 0], x[p * 3 + 1], x[p * 3 + 2], 0.f);
      oid[slot] = p;
    }
  }
}

#define ACC8(off, U, W) {                                  \
  fv[(off)+0] += (W) * __uint_as_float((U).x << 16);       \
  fv[(off)+1] += (W) * __uint_as_float((U).x & 0xffff0000u);\
  fv[(off)+2] += (W) * __uint_as_float((U).y << 16);       \
  fv[(off)+3] += (W) * __uint_as_float((U).y & 0xffff0000u);\
  fv[(off)+4] += (W) * __uint_as_float((U).z << 16);       \
  fv[(off)+5] += (W) * __uint_as_float((U).z & 0xffff0000u);\
  fv[(off)+6] += (W) * __uint_as_float((U).w << 16);       \
  fv[(off)+7] += (W) * __uint_as_float((U).w & 0xffff0000u);\
}

#define MFMA(A,B,C) __builtin_amdgcn_mfma_f32_16x16x32_bf16((A),(B),(C),0,0,0)

// pair P (tiles mt=2P, 2P+1): read both tiles' A-frags (4 k-frags each)
#define HREAD(P, A0,A1,A2,A3, B0,B1,B2,B3) {               \
  const char* ap_ = act + ((P)*32 + c) * ROWB + q * 16;    \
  const char* bp_ = ap_ + 16 * ROWB;                       \
  A0 = *(const short8*)(ap_);       A1 = *(const short8*)(ap_ + 64);  \
  A2 = *(const short8*)(ap_ + 128); A3 = *(const short8*)(ap_ + 192); \
  B0 = *(const short8*)(bp_);       B1 = *(const short8*)(bp_ + 64);  \
  B2 = *(const short8*)(bp_ + 128); B3 = *(const short8*)(bp_ + 192); \
}

#define HZERO2(AVA, AVB) { _Pragma("unroll")               \
  for (int t = 0; t < 8; ++t) { AVA[t] = f32x4{0.f,0.f,0.f,0.f}; AVB[t] = f32x4{0.f,0.f,0.f,0.f}; } }

// K=128 pair MFMA: both tiles interleaved per t
#define HMFMA2(A0,A1,A2,A3, B0,B1,B2,B3, AVA, AVB) { _Pragma("unroll") \
  for (int t = 0; t < 8; ++t) {                            \
    AVA[t] = MFMA(A0, bw[t*4+0], AVA[t]);                  \
    AVA[t] = MFMA(A1, bw[t*4+1], AVA[t]);                  \
    AVA[t] = MFMA(A2, bw[t*4+2], AVA[t]);                  \
    AVA[t] = MFMA(A3, bw[t*4+3], AVA[t]);                  \
    AVB[t] = MFMA(B0, bw[t*4+0], AVB[t]);                  \
    AVB[t] = MFMA(B1, bw[t*4+1], AVB[t]);                  \
    AVB[t] = MFMA(B2, bw[t*4+2], AVB[t]);                  \
    AVB[t] = MFMA(B3, bw[t*4+3], AVB[t]); } }

// K=64 (layer-in) pair MFMA
#define IMFMA2(A0,A1, B0,B1, AVA, AVB) { _Pragma("unroll") \
  for (int t = 0; t < 8; ++t) {                            \
    AVA[t] = MFMA(A0, bwin[t*2+0], AVA[t]);                \
    AVA[t] = MFMA(A1, bwin[t*2+1], AVA[t]);                \
    AVB[t] = MFMA(B0, bwin[t*2+0], AVB[t]);                \
    AVB[t] = MFMA(B1, bwin[t*2+1], AVB[t]); } }

// relu -> bf16 -> LDS for pair P (rows [32P, 32P+32))
#define HEPI(P, AVA, AVB) {                                \
  char* yA_ = act + ((P)*32 + q * 4) * ROWB + c * 2;       \
  char* yB_ = yA_ + 16 * ROWB;                             \
  _Pragma("unroll") for (int t = 0; t < 8; ++t)            \
    _Pragma("unroll") for (int r = 0; r < 4; ++r) {        \
      *(ushort*)(yA_ + r * ROWB + t * 32) = (ushort)f2bf(fmaxf(AVA[t][r], 0.f)); \
      *(ushort*)(yB_ + r * ROWB + t * 32) = (ushort)f2bf(fmaxf(AVB[t][r], 0.f)); } }

// h2 output epilogue for pair P: wout dot + shuffle reduce + scatter store
#define OEPI(P, AVA, AVB) { _Pragma("unroll")              \
  for (int r = 0; r < 4; ++r) {                            \
    float yA = 0.f, yB = 0.f;                              \
    _Pragma("unroll") for (int t = 0; t < 8; ++t) {        \
      yA += fmaxf(AVA[t][r], 0.f) * wo[t];                 \
      yB += fmaxf(AVB[t][r], 0.f) * wo[t]; }               \
    yA += __shfl_xor(yA, 1, 64); yA += __shfl_xor(yA, 2, 64); \
    yA += __shfl_xor(yA, 4, 64); yA += __shfl_xor(yA, 8, 64); \
    yB += __shfl_xor(yB, 1, 64); yB += __shfl_xor(yB, 2, 64); \
    yB += __shfl_xor(yB, 4, 64); yB += __shfl_xor(yB, 8, 64); \
    if (c == r) {                                          \
      int slotA = base + (P)*32 + q * 4 + r;               \
      out[oid[slotA]] = yA;                                \
      out[oid[slotA + 16]] = yB; } } }

// ---- main fused kernel: 4 waves x 128 pts/wave; slab-affine slots ----
// r8 green math; change: pair-level software pipeline (READ(p+1); EPI(p-1);
// MFMA(p+1)) with NO fences inside a layer — scheduler interleaves epilogue
// VALU into MFMA issue gaps. All intra-layer hazards are same-wave LDS
// (in-order pipe) on provably-disjoint rows. Registers free: LDS caps us at
// 1 wave/SIMD, so up to 512 unified VGPR/AGPR per wave.
__global__ __launch_bounds__(256, 1) void k_main(
    const float4* __restrict__ xs, const int* __restrict__ oid,
    const float* __restrict__ wout,
    const ushort* __restrict__ gridb, const ushort* __restrict__ wfrag,
    float* __restrict__ out) {
  extern __shared__ char smem[];
  const int wave = threadIdx.x >> 6;
  const int lane = threadIdx.x & 63;
  const int q = lane >> 4, c = lane & 15;
  char* act = smem + wave * (PW * ROWB);
  const int b = blockIdx.x;
  const int base = (b & 7) * CAP + (b >> 3) * 512 + wave * PW;   // slot base

  // hoisted loads: layer-in weight frags + wout column (hide under gather)
  short8 bwin[16];
#pragma unroll
  for (int f = 0; f < 16; ++f)
    bwin[f] = *(const short8*)(wfrag + f * 512 + lane * 8);
  float wo[8];
#pragma unroll
  for (int t = 0; t < 8; ++t) wo[t] = wout[t * 16 + c];

  // ======== gather + positional encoding: 2 points per lane ========
#pragma unroll
  for (int pp = 0; pp < 2; ++pp) {
    const int p = pp * 64 + lane;
    const float4 c4 = xs[base + p];
    const float px = c4.x;
    const float py = c4.y;
    const float pz = c4.z;
    float fx = (px + 1.0f) * 0.5f * 95.0f;   // x -> W
    float fy = (py + 1.0f) * 0.5f * 95.0f;   // y -> H
    float fz = (pz + 1.0f) * 0.5f * 95.0f;   // z -> D
    float x0f = floorf(fx), y0f = floorf(fy), z0f = floorf(fz);
    float tx = fx - x0f, ty = fy - y0f, tz = fz - z0f;
    int x0i = min(max((int)x0f, 0), 95);
    int y0i = min(max((int)y0f, 0), 95);
    int z0i = min(max((int)z0f, 0), 95);
    int x1i = min(x0i + 1, 95);
    int y1i = min(y0i + 1, 95);
    int z1i = min(z0i + 1, 95);
    float fv[16];
#pragma unroll
    for (int k = 0; k < 16; ++k) fv[k] = 0.f;
#pragma unroll
    for (int dz = 0; dz < 2; ++dz) {
      const int zi = dz ? z1i : z0i;
      const float wz = dz ? tz : (1.f - tz);
#pragma unroll
      for (int dy = 0; dy < 2; ++dy) {
        const int yi = dy ? y1i : y0i;
        const float wzy = wz * (dy ? ty : (1.f - ty));
        const ushort* r0 = gridb + (size_t)(zi * GD2 + yi * GD + x0i) * 16;
        const ushort* r1 = gridb + (size_t)(zi * GD2 + yi * GD + x1i) * 16;
        uint4 a0 = *(const uint4*)r0;
        uint4 a1 = *(const uint4*)(r0 + 8);
        uint4 b0 = *(const uint4*)r1;
        uint4 b1 = *(const uint4*)(r1 + 8);
        const float w0 = wzy * (1.f - tx), w1 = wzy * tx;
        ACC8(0, a0, w0); ACC8(8, a1, w0);
        ACC8(0, b0, w1); ACC8(8, b1, w1);
      }
    }
    float row[64];
#pragma unroll
    for (int i = 0; i < 6; ++i) {
      const float fr = 3.14159265358979323846f * (float)(1 << i);
      row[i*6+0] = __sinf(px*fr); row[i*6+1] = __sinf(py*fr); row[i*6+2] = __sinf(pz*fr);
      row[i*6+3] = __cosf(px*fr); row[i*6+4] = __cosf(py*fr); row[i*6+5] = __cosf(pz*fr);
    }
#pragma unroll
    for (int k = 0; k < 16; ++k) row[36 + k] = fv[k];
#pragma unroll
    for (int k = 52; k < 64; ++k) row[k] = 0.f;
    char* dst = act + p * ROWB;
#pragma unroll
    for (int k = 0; k < 64; k += 8) {
      uint u0 = f2bf(row[k+0]) | (f2bf(row[k+1]) << 16);
      uint u1 = f2bf(row[k+2]) | (f2bf(row[k+3]) << 16);
      uint u2 = f2bf(row[k+4]) | (f2bf(row[k+5]) << 16);
      uint u3 = f2bf(row[k+6]) | (f2bf(row[k+7]) << 16);
      *(uint4*)(dst + k * 2) = make_uint4(u0, u1, u2, u3);
    }
  }
  asm volatile("s_waitcnt lgkmcnt(0)" ::: "memory");

  // ======== layer-in: X[128x64] @ w_in[64x128] -> relu -> act ========
  {
    short8 xA0, xA1, xB0, xB1, yA0, yA1, yB0, yB1;
    f32x4 ac0A[8], ac0B[8], ac1A[8], ac1B[8];
    // pair 0
    {
      const char* ap_ = act + c * ROWB + q * 16;
      const char* bp_ = ap_ + 16 * ROWB;
      xA0 = *(const short8*)(ap_); xA1 = *(const short8*)(ap_ + 64);
      xB0 = *(const short8*)(bp_); xB1 = *(const short8*)(bp_ + 64);
    }
    HZERO2(ac0A, ac0B);
    IMFMA2(xA0, xA1, xB0, xB1, ac0A, ac0B);
    // pair 1
    {
      const char* ap_ = act + (32 + c) * ROWB + q * 16;
      const char* bp_ = ap_ + 16 * ROWB;
      yA0 = *(const short8*)(ap_); yA1 = *(const short8*)(ap_ + 64);
      yB0 = *(const short8*)(bp_); yB1 = *(const short8*)(bp_ + 64);
    }
    HZERO2(ac1A, ac1B);
    HEPI(0, ac0A, ac0B);
    IMFMA2(yA0, yA1, yB0, yB1, ac1A, ac1B);
    // pair 2
    {
      const char* ap_ = act + (64 + c) * ROWB + q * 16;
      const char* bp_ = ap_ + 16 * ROWB;
      xA0 = *(const short8*)(ap_); xA1 = *(const short8*)(ap_ + 64);
      xB0 = *(const short8*)(bp_); xB1 = *(const short8*)(bp_ + 64);
    }
    HZERO2(ac0A, ac0B);
    HEPI(1, ac1A, ac1B);
    IMFMA2(xA0, xA1, xB0, xB1, ac0A, ac0B);
    // pair 3
    {
      const char* ap_ = act + (96 + c) * ROWB + q * 16;
      const char* bp_ = ap_ + 16 * ROWB;
      yA0 = *(const short8*)(ap_); yA1 = *(const short8*)(ap_ + 64);
      yB0 = *(const short8*)(bp_); yB1 = *(const short8*)(bp_ + 64);
    }
    HZERO2(ac1A, ac1B);
    HEPI(2, ac0A, ac0B);
    IMFMA2(yA0, yA1, yB0, yB1, ac1A, ac1B);
    HEPI(3, ac1A, ac1B);
  }
  asm volatile("s_waitcnt lgkmcnt(0)" ::: "memory");

  // ======== hidden layers h0,h1 (relu->act) and h2 (+w_out dot, store) ========
  for (int l = 0; l < 3; ++l) {
    const ushort* wl = wfrag + WIN_ELTS + l * WH_ELTS;
    short8 bw[32];
#pragma unroll
    for (int f = 0; f < 32; ++f)
      bw[f] = *(const short8*)(wl + f * 512 + lane * 8);
    short8 xA0, xA1, xA2, xA3, xB0, xB1, xB2, xB3;
    short8 yA0, yA1, yA2, yA3, yB0, yB1, yB2, yB3;
    f32x4 ac0A[8], ac0B[8], ac1A[8], ac1B[8];
    if (l < 2) {
      HREAD(0, xA0, xA1, xA2, xA3, xB0, xB1, xB2, xB3);
      HZERO2(ac0A, ac0B);
      HMFMA2(xA0, xA1, xA2, xA3, xB0, xB1, xB2, xB3, ac0A, ac0B);

      HREAD(1, yA0, yA1, yA2, yA3, yB0, yB1, yB2, yB3);
      HZERO2(ac1A, ac1B);
      HEPI(0, ac0A, ac0B);
      HMFMA2(yA0, yA1, yA2, yA3, yB0, yB1, yB2, yB3, ac1A, ac1B);

      HREAD(2, xA0, xA1, xA2, xA3, xB0, xB1, xB2, xB3);
      HZERO2(ac0A, ac0B);
      HEPI(1, ac1A, ac1B);
      HMFMA2(xA0, xA1, xA2, xA3, xB0, xB1, xB2, xB3, ac0A, ac0B);

      HREAD(3, yA0, yA1, yA2, yA3, yB0, yB1, yB2, yB3);
      HZERO2(ac1A, ac1B);
      HEPI(2, ac0A, ac0B);
      HMFMA2(yA0, yA1, yA2, yA3, yB0, yB1, yB2, yB3, ac1A, ac1B);

      HEPI(3, ac1A, ac1B);
      asm volatile("s_waitcnt lgkmcnt(0)" ::: "memory");
    } else {
      HREAD(0, xA0, xA1, xA2, xA3, xB0, xB1, xB2, xB3);
      HZERO2(ac0A, ac0B);
      HMFMA2(xA0, xA1, xA2, xA3, xB0, xB1, xB2, xB3, ac0A, ac0B);

      HREAD(1, yA0, yA1, yA2, yA3, yB0, yB1, yB2, yB3);
      HZERO2(ac1A, ac1B);
      OEPI(0, ac0A, ac0B);
      HMFMA2(yA0, yA1, yA2, yA3, yB0, yB1, yB2, yB3, ac1A, ac1B);

      HREAD(2, xA0, xA1, xA2, xA3, xB0, xB1, xB2, xB3);
      HZERO2(ac0A, ac0B);
      OEPI(1, ac1A, ac1B);
      HMFMA2(xA0, xA1, xA2, xA3, xB0, xB1, xB2, xB3, ac0A, ac0B);

      HREAD(3, yA0, yA1, yA2, yA3, yB0, yB1, yB2, yB3);
      HZERO2(ac1A, ac1B);
      OEPI(2, ac0A, ac0B);
      HMFMA2(yA0, yA1, yA2, yA3, yB0, yB1, yB2, yB3, ac1A, ac1B);

      OEPI(3, ac1A, ac1B);
    }
  }
}

extern "C" void kernel_launch(void* const* d_in, const int* in_sizes, int n_in,
                              void* d_out, int out_size, void* d_ws, size_t ws_size,
                              hipStream_t stream) {
  const float* x    = (const float*)d_in[0];
  const float* fg   = (const float*)d_in[1];
  const float* win  = (const float*)d_in[2];
  const float* wh0  = (const float*)d_in[3];
  const float* wh1  = (const float*)d_in[4];
  const float* wh2  = (const float*)d_in[5];
  const float* wout = (const float*)d_in[6];
  float* out = (float*)d_out;

  char* wsb = (char*)d_ws;
  ushort* gridb  = (ushort*)d_ws;                      // 28,311,552 B
  ushort* wfrag  = (ushort*)d_ws + WFRAG_OFF;          // +114,688 B
  float4* xs     = (float4*)(wsb + XS_BYTE);           // 16.8 MB
  int*    oid    = (int*)(wsb + OID_BYTE);             // 4.2 MB
  int*    cursor = (int*)(wsb + CUR_BYTE);             // 32 B

  k_grid_pack<<<GSP / 256, 256, 0, stream>>>(fg, gridb);
  k_w_pack<<<(WIN_ELTS + 3 * WH_ELTS) / 256, 256, 0, stream>>>(win, wh0, wh1, wh2, wfrag);
  k_prefill<<<NSLOT / 256, 256, 0, stream>>>(x, xs, oid, cursor);
  k_scatter<<<(NPTS + 4095) / 4096, 256, 0, stream>>>(x, xs, oid, cursor);

  k_main<<<NSLAB * (CAP / 512), 256, LDS_BYTES, stream>>>(xs, oid, wout, gridb, wfrag, out);
}

// Round 11
// 375.039 us; speedup vs baseline: 1.3662x; 1.0299x over previous
//
#include <hip/hip_runtime.h>
#include <stdint.h>

typedef unsigned int uint;
typedef unsigned short ushort;

#define GD   96
#define GD2  (GD*GD)           // 9216
#define GSP  (GD*GD*GD)        // 884736 spatial cells
#define NPTS 1000000
#define WIN_ELTS 8192          // padded w_in frags: 64x128
#define WH_ELTS  16384         // 128x128
#define WFRAG_OFF (GSP*16)     // ushort offset of weight frags in ws

#define PW   128               // points per wave (proven geometry — PW=64 is cursed, closed)
#define ROWB 272               // LDS activation row stride bytes (136 bf16: 128 + 8 pad)
#define LDS_BYTES (4*PW*ROWB)  // 139264

#define GP_BLOCKS (GSP/256)            // 3456 grid-pack blocks
#define WP_BLOCKS ((WIN_ELTS+3*WH_ELTS)/256)  // 224 w-pack blocks

typedef __attribute__((ext_vector_type(8))) short short8;
typedef __attribute__((ext_vector_type(4))) float f32x4;

__device__ __forceinline__ uint f2bf(float x) {           // fp32 -> bf16 (RNE)
  uint u = __float_as_uint(x);
  return (u + 0x7fffu + ((u >> 16) & 1u)) >> 16;
}

// ---- merged pre-pass: feature-grid repack + weight frag pack (1 launch) ----
__global__ void k_pre(const float* __restrict__ g,
                      const float* __restrict__ win, const float* __restrict__ h0,
                      const float* __restrict__ h1, const float* __restrict__ h2,
                      ushort* __restrict__ ogrid, ushort* __restrict__ owf) {
  const int blk = blockIdx.x;
  if (blk < GP_BLOCKS) {
    int sp = blk * 256 + threadIdx.x;   // 0..884735
    uint pk[8];
#pragma unroll
    for (int c = 0; c < 16; c += 2) {
      float a = g[(size_t)c * GSP + sp];
      float b = g[(size_t)(c + 1) * GSP + sp];
      pk[c >> 1] = f2bf(a) | (f2bf(b) << 16);
    }
    uint4* dst = (uint4*)(ogrid + (size_t)sp * 16);
    dst[0] = make_uint4(pk[0], pk[1], pk[2], pk[3]);
    dst[1] = make_uint4(pk[4], pk[5], pk[6], pk[7]);
  } else {
    int tid = (blk - GP_BLOCKS) * 256 + threadIdx.x;  // < 57344
    int lane = (tid >> 3) & 63, j = tid & 7;
    int q = lane >> 4, cc = lane & 15;
    float v;
    if (tid < WIN_ELTS) {
      int b2 = tid >> 9;
      int t = b2 >> 1, s = b2 & 1;
      int k = s * 32 + q * 8 + j, n = t * 16 + cc;
      v = (k < 52) ? win[k * 128 + n] : 0.f;
    } else {
      int f2 = tid - WIN_ELTS;
      int l = f2 >> 14, r = f2 & 16383;
      int b2 = r >> 9;
      int t = b2 >> 2, s = b2 & 3;
      int k = s * 32 + q * 8 + j, n = t * 16 + cc;
      const float* w = (l == 0) ? h0 : ((l == 1) ? h1 : h2);
      v = w[k * 128 + n];
    }
    owf[tid] = (ushort)f2bf(v);
  }
}

#define ACC8(off, U, W) {                                  \
  fv[(off)+0] += (W) * __uint_as_float((U).x << 16);       \
  fv[(off)+1] += (W) * __uint_as_float((U).x & 0xffff0000u);\
  fv[(off)+2] += (W) * __uint_as_float((U).y << 16);       \
  fv[(off)+3] += (W) * __uint_as_float((U).y & 0xffff0000u);\
  fv[(off)+4] += (W) * __uint_as_float((U).z << 16);       \
  fv[(off)+5] += (W) * __uint_as_float((U).z & 0xffff0000u);\
  fv[(off)+6] += (W) * __uint_as_float((U).w << 16);       \
  fv[(off)+7] += (W) * __uint_as_float((U).w & 0xffff0000u);\
}

#define MFMA(A,B,C) __builtin_amdgcn_mfma_f32_16x16x32_bf16((A),(B),(C),0,0,0)

// pair P (tiles mt=2P, 2P+1): read both tiles' A-frags (4 k-frags each)
#define HREAD(P, A0,A1,A2,A3, B0,B1,B2,B3) {               \
  const char* ap_ = act + ((P)*32 + c) * ROWB + q * 16;    \
  const char* bp_ = ap_ + 16 * ROWB;                       \
  A0 = *(const short8*)(ap_);       A1 = *(const short8*)(ap_ + 64);  \
  A2 = *(const short8*)(ap_ + 128); A3 = *(const short8*)(ap_ + 192); \
  B0 = *(const short8*)(bp_);       B1 = *(const short8*)(bp_ + 64);  \
  B2 = *(const short8*)(bp_ + 128); B3 = *(const short8*)(bp_ + 192); \
}

#define HZERO2(AVA, AVB) { _Pragma("unroll")               \
  for (int t = 0; t < 8; ++t) { AVA[t] = f32x4{0.f,0.f,0.f,0.f}; AVB[t] = f32x4{0.f,0.f,0.f,0.f}; } }

// K=128 pair MFMA: both tiles interleaved per t
#define HMFMA2(A0,A1,A2,A3, B0,B1,B2,B3, AVA, AVB) { _Pragma("unroll") \
  for (int t = 0; t < 8; ++t) {                            \
    AVA[t] = MFMA(A0, bw[t*4+0], AVA[t]);                  \
    AVA[t] = MFMA(A1, bw[t*4+1], AVA[t]);                  \
    AVA[t] = MFMA(A2, bw[t*4+2], AVA[t]);                  \
    AVA[t] = MFMA(A3, bw[t*4+3], AVA[t]);                  \
    AVB[t] = MFMA(B0, bw[t*4+0], AVB[t]);                  \
    AVB[t] = MFMA(B1, bw[t*4+1], AVB[t]);                  \
    AVB[t] = MFMA(B2, bw[t*4+2], AVB[t]);                  \
    AVB[t] = MFMA(B3, bw[t*4+3], AVB[t]); } }

// K=64 (layer-in) pair MFMA
#define IMFMA2(A0,A1, B0,B1, AVA, AVB) { _Pragma("unroll") \
  for (int t = 0; t < 8; ++t) {                            \
    AVA[t] = MFMA(A0, bwin[t*2+0], AVA[t]);                \
    AVA[t] = MFMA(A1, bwin[t*2+1], AVA[t]);                \
    AVB[t] = MFMA(B0, bwin[t*2+0], AVB[t]);                \
    AVB[t] = MFMA(B1, bwin[t*2+1], AVB[t]); } }

// relu -> bf16 -> LDS for pair P (rows [32P, 32P+32))
#define HEPI(P, AVA, AVB) {                                \
  char* yA_ = act + ((P)*32 + q * 4) * ROWB + c * 2;       \
  char* yB_ = yA_ + 16 * ROWB;                             \
  _Pragma("unroll") for (int t = 0; t < 8; ++t)            \
    _Pragma("unroll") for (int r = 0; r < 4; ++r) {        \
      *(ushort*)(yA_ + r * ROWB + t * 32) = (ushort)f2bf(fmaxf(AVA[t][r], 0.f)); \
      *(ushort*)(yB_ + r * ROWB + t * 32) = (ushort)f2bf(fmaxf(AVB[t][r], 0.f)); } }

// h2 output epilogue for pair P: wout dot + shuffle reduce + direct store
#define OEPI(P, AVA, AVB) { _Pragma("unroll")              \
  for (int r = 0; r < 4; ++r) {                            \
    float yA = 0.f, yB = 0.f;                              \
    _Pragma("unroll") for (int t = 0; t < 8; ++t) {        \
      yA += fmaxf(AVA[t][r], 0.f) * wo[t];                 \
      yB += fmaxf(AVB[t][r], 0.f) * wo[t]; }               \
    yA += __shfl_xor(yA, 1, 64); yA += __shfl_xor(yA, 2, 64); \
    yA += __shfl_xor(yA, 4, 64); yA += __shfl_xor(yA, 8, 64); \
    yB += __shfl_xor(yB, 1, 64); yB += __shfl_xor(yB, 2, 64); \
    yB += __shfl_xor(yB, 4, 64); yB += __shfl_xor(yB, 8, 64); \
    if (c == r) {                                          \
      int gpo = base + (P)*32 + q * 4 + r;                 \
      if (gpo < NPTS) out[gpo] = yA;                       \
      int gpo2 = gpo + 16;                                 \
      if (gpo2 < NPTS) out[gpo2] = yB; } } }

// ---- main fused kernel: 4 waves x 128 pts/wave; direct point indexing ----
// r10-green pipelined MLP; binning removed (r6 proved FETCH 279->56MB had
// ZERO k_main time effect — gather is latency-bound, not BW-bound).
__global__ __launch_bounds__(256, 1) void k_main(
    const float* __restrict__ x, const float* __restrict__ wout,
    const ushort* __restrict__ gridb, const ushort* __restrict__ wfrag,
    float* __restrict__ out) {
  extern __shared__ char smem[];
  const int wave = threadIdx.x >> 6;
  const int lane = threadIdx.x & 63;
  const int q = lane >> 4, c = lane & 15;
  char* act = smem + wave * (PW * ROWB);
  const int base = blockIdx.x * (4 * PW) + wave * PW;

  // hoisted loads: layer-in weight frags + wout column (hide under gather)
  short8 bwin[16];
#pragma unroll
  for (int f = 0; f < 16; ++f)
    bwin[f] = *(const short8*)(wfrag + f * 512 + lane * 8);
  float wo[8];
#pragma unroll
  for (int t = 0; t < 8; ++t) wo[t] = wout[t * 16 + c];

  // ======== gather + positional encoding: 2 points per lane ========
#pragma unroll
  for (int pp = 0; pp < 2; ++pp) {
    const int p = pp * 64 + lane;
    const int gp = base + p;
    const int gpc = min(gp, NPTS - 1);
    const float px = x[gpc * 3 + 0];
    const float py = x[gpc * 3 + 1];
    const float pz = x[gpc * 3 + 2];
    float fx = (px + 1.0f) * 0.5f * 95.0f;   // x -> W
    float fy = (py + 1.0f) * 0.5f * 95.0f;   // y -> H
    float fz = (pz + 1.0f) * 0.5f * 95.0f;   // z -> D
    float x0f = floorf(fx), y0f = floorf(fy), z0f = floorf(fz);
    float tx = fx - x0f, ty = fy - y0f, tz = fz - z0f;
    int x0i = min(max((int)x0f, 0), 95);
    int y0i = min(max((int)y0f, 0), 95);
    int z0i = min(max((int)z0f, 0), 95);
    int x1i = min(x0i + 1, 95);
    int y1i = min(y0i + 1, 95);
    int z1i = min(z0i + 1, 95);
    float fv[16];
#pragma unroll
    for (int k = 0; k < 16; ++k) fv[k] = 0.f;
#pragma unroll
    for (int dz = 0; dz < 2; ++dz) {
      const int zi = dz ? z1i : z0i;
      const float wz = dz ? tz : (1.f - tz);
#pragma unroll
      for (int dy = 0; dy < 2; ++dy) {
        const int yi = dy ? y1i : y0i;
        const float wzy = wz * (dy ? ty : (1.f - ty));
        const ushort* r0 = gridb + (size_t)(zi * GD2 + yi * GD + x0i) * 16;
        const ushort* r1 = gridb + (size_t)(zi * GD2 + yi * GD + x1i) * 16;
        uint4 a0 = *(const uint4*)r0;
        uint4 a1 = *(const uint4*)(r0 + 8);
        uint4 b0 = *(const uint4*)r1;
        uint4 b1 = *(const uint4*)(r1 + 8);
        const float w0 = wzy * (1.f - tx), w1 = wzy * tx;
        ACC8(0, a0, w0); ACC8(8, a1, w0);
        ACC8(0, b0, w1); ACC8(8, b1, w1);
      }
    }
    float row[64];
#pragma unroll
    for (int i = 0; i < 6; ++i) {
      const float fr = 3.14159265358979323846f * (float)(1 << i);
      row[i*6+0] = __sinf(px*fr); row[i*6+1] = __sinf(py*fr); row[i*6+2] = __sinf(pz*fr);
      row[i*6+3] = __cosf(px*fr); row[i*6+4] = __cosf(py*fr); row[i*6+5] = __cosf(pz*fr);
    }
#pragma unroll
    for (int k = 0; k < 16; ++k) row[36 + k] = fv[k];
#pragma unroll
    for (int k = 52; k < 64; ++k) row[k] = 0.f;
    char* dst = act + p * ROWB;
#pragma unroll
    for (int k = 0; k < 64; k += 8) {
      uint u0 = f2bf(row[k+0]) | (f2bf(row[k+1]) << 16);
      uint u1 = f2bf(row[k+2]) | (f2bf(row[k+3]) << 16);
      uint u2 = f2bf(row[k+4]) | (f2bf(row[k+5]) << 16);
      uint u3 = f2bf(row[k+6]) | (f2bf(row[k+7]) << 16);
      *(uint4*)(dst + k * 2) = make_uint4(u0, u1, u2, u3);
    }
  }
  asm volatile("s_waitcnt lgkmcnt(0)" ::: "memory");

  // ======== layer-in: X[128x64] @ w_in[64x128] -> relu -> act ========
  {
    short8 xA0, xA1, xB0, xB1, yA0, yA1, yB0, yB1;
    f32x4 ac0A[8], ac0B[8], ac1A[8], ac1B[8];
    // pair 0
    {
      const char* ap_ = act + c * ROWB + q * 16;
      const char* bp_ = ap_ + 16 * ROWB;
      xA0 = *(const short8*)(ap_); xA1 = *(const short8*)(ap_ + 64);
      xB0 = *(const short8*)(bp_); xB1 = *(const short8*)(bp_ + 64);
    }
    HZERO2(ac0A, ac0B);
    IMFMA2(xA0, xA1, xB0, xB1, ac0A, ac0B);
    // pair 1
    {
      const char* ap_ = act + (32 + c) * ROWB + q * 16;
      const char* bp_ = ap_ + 16 * ROWB;
      yA0 = *(const short8*)(ap_); yA1 = *(const short8*)(ap_ + 64);
      yB0 = *(const short8*)(bp_); yB1 = *(const short8*)(bp_ + 64);
    }
    HZERO2(ac1A, ac1B);
    HEPI(0, ac0A, ac0B);
    IMFMA2(yA0, yA1, yB0, yB1, ac1A, ac1B);
    // pair 2
    {
      const char* ap_ = act + (64 + c) * ROWB + q * 16;
      const char* bp_ = ap_ + 16 * ROWB;
      xA0 = *(const short8*)(ap_); xA1 = *(const short8*)(ap_ + 64);
      xB0 = *(const short8*)(bp_); xB1 = *(const short8*)(bp_ + 64);
    }
    HZERO2(ac0A, ac0B);
    HEPI(1, ac1A, ac1B);
    IMFMA2(xA0, xA1, xB0, xB1, ac0A, ac0B);
    // pair 3
    {
      const char* ap_ = act + (96 + c) * ROWB + q * 16;
      const char* bp_ = ap_ + 16 * ROWB;
      yA0 = *(const short8*)(ap_); yA1 = *(const short8*)(ap_ + 64);
      yB0 = *(const short8*)(bp_); yB1 = *(const short8*)(bp_ + 64);
    }
    HZERO2(ac1A, ac1B);
    HEPI(2, ac0A, ac0B);
    IMFMA2(yA0, yA1, yB0, yB1, ac1A, ac1B);
    HEPI(3, ac1A, ac1B);
  }
  asm volatile("s_waitcnt lgkmcnt(0)" ::: "memory");

  // ======== hidden layers h0,h1 (relu->act) and h2 (+w_out dot, store) ========
  for (int l = 0; l < 3; ++l) {
    const ushort* wl = wfrag + WIN_ELTS + l * WH_ELTS;
    short8 bw[32];
#pragma unroll
    for (int f = 0; f < 32; ++f)
      bw[f] = *(const short8*)(wl + f * 512 + lane * 8);
    short8 xA0, xA1, xA2, xA3, xB0, xB1, xB2, xB3;
    short8 yA0, yA1, yA2, yA3, yB0, yB1, yB2, yB3;
    f32x4 ac0A[8], ac0B[8], ac1A[8], ac1B[8];
    if (l < 2) {
      HREAD(0, xA0, xA1, xA2, xA3, xB0, xB1, xB2, xB3);
      HZERO2(ac0A, ac0B);
      HMFMA2(xA0, xA1, xA2, xA3, xB0, xB1, xB2, xB3, ac0A, ac0B);

      HREAD(1, yA0, yA1, yA2, yA3, yB0, yB1, yB2, yB3);
      HZERO2(ac1A, ac1B);
      HEPI(0, ac0A, ac0B);
      HMFMA2(yA0, yA1, yA2, yA3, yB0, yB1, yB2, yB3, ac1A, ac1B);

      HREAD(2, xA0, xA1, xA2, xA3, xB0, xB1, xB2, xB3);
      HZERO2(ac0A, ac0B);
      HEPI(1, ac1A, ac1B);
      HMFMA2(xA0, xA1, xA2, xA3, xB0, xB1, xB2, xB3, ac0A, ac0B);

      HREAD(3, yA0, yA1, yA2, yA3, yB0, yB1, yB2, yB3);
      HZERO2(ac1A, ac1B);
      HEPI(2, ac0A, ac0B);
      HMFMA2(yA0, yA1, yA2, yA3, yB0, yB1, yB2, yB3, ac1A, ac1B);

      HEPI(3, ac1A, ac1B);
      asm volatile("s_waitcnt lgkmcnt(0)" ::: "memory");
    } else {
      HREAD(0, xA0, xA1, xA2, xA3, xB0, xB1, xB2, xB3);
      HZERO2(ac0A, ac0B);
      HMFMA2(xA0, xA1, xA2, xA3, xB0, xB1, xB2, xB3, ac0A, ac0B);

      HREAD(1, yA0, yA1, yA2, yA3, yB0, yB1, yB2, yB3);
      HZERO2(ac1A, ac1B);
      OEPI(0, ac0A, ac0B);
      HMFMA2(yA0, yA1, yA2, yA3, yB0, yB1, yB2, yB3, ac1A, ac1B);

      HREAD(2, xA0, xA1, xA2, xA3, xB0, xB1, xB2, xB3);
      HZERO2(ac0A, ac0B);
      OEPI(1, ac1A, ac1B);
      HMFMA2(xA0, xA1, xA2, xA3, xB0, xB1, xB2, xB3, ac0A, ac0B);

      HREAD(3, yA0, yA1, yA2, yA3, yB0, yB1, yB2, yB3);
      HZERO2(ac1A, ac1B);
      OEPI(2, ac0A, ac0B);
      HMFMA2(yA0, yA1, yA2, yA3, yB0, yB1, yB2, yB3, ac1A, ac1B);

      OEPI(3, ac1A, ac1B);
    }
  }
}

extern "C" void kernel_launch(void* const* d_in, const int* in_sizes, int n_in,
                              void* d_out, int out_size, void* d_ws, size_t ws_size,
                              hipStream_t stream) {
  const float* x    = (const float*)d_in[0];
  const float* fg   = (const float*)d_in[1];
  const float* win  = (const float*)d_in[2];
  const float* wh0  = (const float*)d_in[3];
  const float* wh1  = (const float*)d_in[4];
  const float* wh2  = (const float*)d_in[5];
  const float* wout = (const float*)d_in[6];
  float* out = (float*)d_out;

  ushort* gridb = (ushort*)d_ws;                       // 28,311,552 B
  ushort* wfrag = (ushort*)d_ws + WFRAG_OFF;           // +114,688 B

  k_pre<<<GP_BLOCKS + WP_BLOCKS, 256, 0, stream>>>(fg, win, wh0, wh1, wh2, gridb, wfrag);

  const int nblk = (NPTS + 4 * PW - 1) / (4 * PW);     // 1954
  k_main<<<nblk, 256, LDS_BYTES, stream>>>(x, wout, gridb, wfrag, out);
}